// Round 10
// baseline (195.110 us; speedup 1.0000x reference)
//
#include <hip/hip_runtime.h>
#include <hip/hip_bf16.h>

#define N_   64
#define D_   128
#define L_   3136
#define K_   64
#define TL_  64
#define NG_  12     // pixel groups per image -> grid = 64*12 = 768 blocks
// tiles per group: g==0 -> 5, else 4 (5 + 11*4 = 49 tiles of 64 pixels)
#define ASH  72     // As row stride in shorts (144B: 16B-aligned rows)

typedef short  short8  __attribute__((ext_vector_type(8)));
typedef short  short4v __attribute__((ext_vector_type(4)));
typedef float  f32x16  __attribute__((ext_vector_type(16)));

static __device__ __forceinline__ unsigned short f2bf(float f) {
    unsigned u = __float_as_uint(f);                       // RNE f32 -> bf16 bits
    return (unsigned short)((u + 0x7FFFu + ((u >> 16) & 1u)) >> 16);
}
static __device__ __forceinline__ float bf2f(short s) {
    return __uint_as_float(((unsigned)(unsigned short)s) << 16);
}
// packed RNE convert: lowers to v_cvt_pk_bf16_f32 (low16 = lo)
static __device__ __forceinline__ unsigned pk2(float lo, float hi) {
    __hip_bfloat162 b = __float22bfloat162_rn(make_float2(lo, hi));
    return *reinterpret_cast<unsigned*>(&b);
}

// Raw barrier: drains LDS (lgkmcnt) for write->barrier->read ordering, but
// does NOT drain vmcnt -- prefetch global loads stay in flight across it.
#define BARX() asm volatile("s_waitcnt lgkmcnt(0)\n\ts_barrier" ::: "memory")

// Full-MFMA fused NetVLAD, software-pipelined, with fused split-image
// finalize: last block per image (device-scope counter) reduces the slabs,
// subtracts asum*c, intra-normalizes, applies global norm 1/sqrt(K)=1/8.
// launch_bounds(256,2): r6/r8 lesson -- (256,3) caps VGPR+AGPR at 128 and
// spills the 32-reg prefetch; (256,2) keeps it in registers.
__global__ __launch_bounds__(256, 2)
void vlad_main(const float* __restrict__ x, const float* __restrict__ w,
               const float* __restrict__ cent, float* __restrict__ out,
               float* __restrict__ vout, float* __restrict__ aout,
               int* __restrict__ counters,   // non-null => slab path + fused tail
               int vstride, int astride)     // vstride==0 => atomic accumulate path
{
    __shared__ __align__(16) short L1[TL_ * D_];   // [l][dk] bf16, swz ^((l&15)<<4), 16KB
    __shared__ __align__(16) short L2[D_ * TL_];   // [dk][l] bf16, swz ^((dk&7)<<4), 16KB
    __shared__ __align__(16) char  AsRaw[K_ * ASH * 2];  // bf16 a*inv [k][p], 9.2KB;
                                                         // rows 0..15 double as f32 red_ss[16][68]
    __shared__ float nrm_lds[TL_];
    __shared__ float dred[4][32];                  // softmax denominator exchange
    __shared__ int   lastf;

    const int t    = threadIdx.x;
    const int lane = t & 63;
    const int wv   = __builtin_amdgcn_readfirstlane(t >> 6);  // 0..3
    const int n    = blockIdx.x / NG_;
    const int g    = blockIdx.x % NG_;
    const int tile0 = (g == 0) ? 0 : (4 * g + 1);
    const int ntile = (g == 0) ? 5 : 4;

    const int Mt = wv & 1;     // cluster-half (M) for both phases
    const int lg = lane >> 5;  // k-element group (0/1)
    const int lm = lane & 31;

    char* L1b = (char*)L1;
    char* L2b = (char*)L2;
    short* AsS = (short*)AsRaw;
    float (*red_ss)[68] = (float (*)[68])AsRaw;    // union: consumed before As written

    // ---- W fragments, loop-invariant, kept in 32 VGPRs ----
    short8 wf[8];
#pragma unroll
    for (int ks = 0; ks < 8; ++ks) {
        const float* wp = w + (size_t)(32 * Mt + lm) * D_ + 16 * ks + 8 * lg;
        const float4 wa = *(const float4*)wp;
        const float4 wb = *(const float4*)(wp + 4);
        union { unsigned u[4]; short8 s; } f;
        f.u[0] = pk2(wa.x, wa.y); f.u[1] = pk2(wa.z, wa.w);
        f.u[2] = pk2(wb.x, wb.y); f.u[3] = pk2(wb.z, wb.w);
        wf[ks] = f.s;
    }

    f32x16 acc0 = {0};   // V[k][d] C-frag, d-tile 2*(wv>>1)
    f32x16 acc1 = {0};   // d-tile 2*(wv>>1)+1
    float asum_acc = 0.f;

    const int q  = t >> 4;          // staging: d-rows 8q..8q+7
    const int l0 = (t & 15) * 4;    // staging: 4 pixels
    const float* xb = x + (size_t)n * D_ * L_;

    // ---- prologue: load tile 0 into registers ----
    float4 v[8];
    {
        const int p0 = tile0 * TL_;
#pragma unroll
        for (int r = 0; r < 8; ++r)
            v[r] = *(const float4*)(xb + (size_t)(8 * q + r) * L_ + p0 + l0);
    }

    for (int ti = 0; ti < ntile; ++ti) {
        // ---- stage current tile from v[]: sumsq + packed bf16 + L1 + L2 ----
#pragma unroll
        for (int j = 0; j < 4; ++j) {
            float s = 0.f;
#pragma unroll
            for (int r = 0; r < 8; ++r) {
                const float val = (&v[r].x)[j];
                s = fmaf(val, val, s);
            }
            red_ss[q][l0 + j] = s;
        }
#pragma unroll
        for (int j = 0; j < 4; ++j) {   // L1: per pixel, 8 consecutive dk (b128)
            const int l = l0 + j;
            union { unsigned u[4]; short8 s; } f;
            f.u[0] = pk2((&v[0].x)[j], (&v[1].x)[j]);
            f.u[1] = pk2((&v[2].x)[j], (&v[3].x)[j]);
            f.u[2] = pk2((&v[4].x)[j], (&v[5].x)[j]);
            f.u[3] = pk2((&v[6].x)[j], (&v[7].x)[j]);
            *(short8*)(L1b + l * 256 + ((16 * q) ^ ((l & 15) << 4))) = f.s;
        }
#pragma unroll
        for (int r = 0; r < 8; ++r) {   // L2: per d, 4 consecutive l (b64)
            const int d = 8 * q + r;
            union { unsigned u[2]; short4v s; } f;
            f.u[0] = pk2(v[r].x, v[r].y);
            f.u[1] = pk2(v[r].z, v[r].w);
            *(short4v*)(L2b + d * 128 + ((l0 * 2) ^ ((d & 7) << 4))) = f.s;
        }
        // ---- issue next tile's loads NOW (v[] just went dead); they stay
        //      in flight across the raw barriers below ----
        if (ti + 1 < ntile) {
            const int p0n = (tile0 + ti + 1) * TL_;
#pragma unroll
            for (int r = 0; r < 8; ++r)
                v[r] = *(const float4*)(xb + (size_t)(8 * q + r) * L_ + p0n + l0);
        }
        BARX();  // A: tile staged (red_ss/L1/L2 visible)
        // ---- per-pixel norm for asum (wave 0) ----
        if (t < TL_) {
            float ss = 0.f;
#pragma unroll
            for (int qq = 0; qq < 16; ++qq) ss += red_ss[qq][t];
            nrm_lds[t] = fmaxf(sqrtf(ss), 1e-12f);
        }
        // ---- phase 1: R = W * X (quadrant Mt x Nt), contraction dk=128 ----
        f32x16 r1 = {0};
        {
            const int l = 32 * (wv >> 1) + lm;   // pixel = col = lane&31
            const int rowoff = l * 256;
            const int swz = (l & 15) << 4;
            __builtin_amdgcn_s_setprio(1);
#pragma unroll
            for (int ks = 0; ks < 8; ++ks) {
                const short8 bfr = *(short8*)(L1b + rowoff + (((16 * ks + 8 * lg) * 2) ^ swz));
                r1 = __builtin_amdgcn_mfma_f32_32x32x16_bf16(wf[ks], bfr, r1, 0, 0, 0);
            }
            __builtin_amdgcn_s_setprio(0);
        }
        // ---- per-thread inv from red_ss ----
        const int myl = 32 * (wv >> 1) + lm;
        float ss16 = 0.f;
#pragma unroll
        for (int qq = 0; qq < 16; ++qq) ss16 += red_ss[qq][myl];
        const float invp = 1.f / fmaxf(sqrtf(ss16), 1e-12f);
        // ---- softmax over k (no max-sub; |logit*inv| <= ||w_k|| ~ 0.6) ----
        float e[16];
        float s = 0.f;
#pragma unroll
        for (int r = 0; r < 16; ++r) { e[r] = __expf(r1[r] * invp); s += e[r]; }
        s += __shfl_xor(s, 32);              // combine the two k-halves per pixel
        if (lane < 32) dred[wv][lm] = s;
        BARX();  // B: dred ready (and red_ss fully consumed)
        const float denom = dred[wv][lm] + dred[wv ^ 1][lm];   // cross-Mt partner
        const float sc = invp / denom;       // A_s = a * inv (agg uses raw X)
        {
            const int colp = 32 * (wv >> 1) + lm;
#pragma unroll
            for (int r = 0; r < 16; ++r) {   // bf16 store: 2B/lane, 2-way alias (free)
                const int k = 32 * Mt + (r & 3) + 8 * (r >> 2) + 4 * lg;
                AsS[k * ASH + colp] = (short)f2bf(e[r] * sc);
            }
        }
        BARX();  // C: A_s ready
        // ---- phase 2: V += A_s * X^T, contraction l=64 (af read direct) ----
        {
            short8 af[4];
            const char* arow = AsRaw + (size_t)(32 * Mt + lm) * (ASH * 2);
#pragma unroll
            for (int ks = 0; ks < 4; ++ks)
                af[ks] = *(const short8*)(arow + (16 * ks + 8 * lg) * 2);
            __builtin_amdgcn_s_setprio(1);
#pragma unroll
            for (int nt = 0; nt < 2; ++nt) {
                const int dk = 32 * (2 * (wv >> 1) + nt) + lm;  // d = col = lane&31
                const int rowoff = dk * 128;
                const int swz = (dk & 7) << 4;
                f32x16 a = (nt == 0) ? acc0 : acc1;
#pragma unroll
                for (int ks = 0; ks < 4; ++ks) {
                    const short8 bfr = *(short8*)(L2b + rowoff + (((16 * ks + 8 * lg) * 2) ^ swz));
                    a = __builtin_amdgcn_mfma_f32_32x32x16_bf16(af[ks], bfr, a, 0, 0, 0);
                }
                if (nt == 0) acc0 = a; else acc1 = a;
            }
            __builtin_amdgcn_s_setprio(0);
        }
        // ---- asum partial: asum[k] += sum_l A_s[k][l]*nrm[l] (bf16 reads) ----
        {
            const int k  = 16 * wv + (lane & 15);
            const int c4 = lane >> 4;                 // l-chunk 16*c4
            const char* ap = AsRaw + (size_t)k * (ASH * 2) + c4 * 32;
            const short8 a0 = *(const short8*)ap;
            const short8 a1 = *(const short8*)(ap + 16);
            float ps = 0.f;
#pragma unroll
            for (int i = 0; i < 8; ++i) {
                ps = fmaf(bf2f(a0[i]), nrm_lds[16 * c4 + i],     ps);
                ps = fmaf(bf2f(a1[i]), nrm_lds[16 * c4 + 8 + i], ps);
            }
            ps += __shfl_xor(ps, 16);
            ps += __shfl_xor(ps, 32);
            asum_acc += ps;
        }
        BARX();  // D: L1/L2/As/nrm consumers done (WAR for next staging)
    }
    // ---- commit: per-group slab (plain stores) or atomic fallback ----
    {
        const int dbase0 = 32 * (2 * (wv >> 1));
        float* vb = vstride ? (vout + (size_t)g * vstride) : vout;
#pragma unroll
        for (int r = 0; r < 16; ++r) {
            const int k = 32 * Mt + (r & 3) + 8 * (r >> 2) + 4 * lg;
            float* row = vb + ((size_t)n * K_ + k) * D_ + lm;
            if (vstride) {
                row[dbase0]      = acc0[r];
                row[dbase0 + 32] = acc1[r];
            } else {
                atomicAdd(&row[dbase0],      acc0[r]);
                atomicAdd(&row[dbase0 + 32], acc1[r]);
            }
        }
        if (lane < 16) {
            const int k = 16 * wv + lane;
            if (astride) aout[(size_t)g * astride + n * K_ + k] = asum_acc;
            else atomicAdd(&aout[n * K_ + k], asum_acc);
        }
    }
    if (!counters) return;
    // ---- fused finalize: last block of image n reduces + normalizes ----
    __threadfence();                        // release commit stores (device scope)
    if (t == 0) lastf = (atomicAdd(&counters[n], 1) == NG_ - 1);
    __syncthreads();
    if (!lastf) return;
    __threadfence();                        // acquire other groups' stores
    {
        const int kk = t >> 2;              // 0..63 (4 threads per k-row)
        const int qq = t & 3;               // d-chunk: 8 float4 = 32 floats
        float a = 0.f;
#pragma unroll
        for (int gg = 0; gg < NG_; ++gg)
            a += aout[(size_t)gg * astride + n * K_ + kk];
        const size_t off4 = (((size_t)(n * K_ + kk)) * D_ >> 2) + qq * 8;
        float4 vv[8];
#pragma unroll
        for (int j = 0; j < 8; ++j) vv[j] = make_float4(0.f, 0.f, 0.f, 0.f);
        for (int gg = 0; gg < NG_; ++gg) {
            const float4* s4 = (const float4*)(vout + (size_t)gg * vstride) + off4;
#pragma unroll
            for (int j = 0; j < 8; ++j) {
                const float4 s = s4[j];
                vv[j].x += s.x; vv[j].y += s.y; vv[j].z += s.z; vv[j].w += s.w;
            }
        }
        const float4* cc4 = (const float4*)cent + (((size_t)kk * D_) >> 2) + qq * 8;
        float ss2 = 0.f;
#pragma unroll
        for (int j = 0; j < 8; ++j) {
            const float4 c4 = cc4[j];
            vv[j].x -= a * c4.x; vv[j].y -= a * c4.y;
            vv[j].z -= a * c4.z; vv[j].w -= a * c4.w;
            ss2 = fmaf(vv[j].x, vv[j].x, ss2); ss2 = fmaf(vv[j].y, vv[j].y, ss2);
            ss2 = fmaf(vv[j].z, vv[j].z, ss2); ss2 = fmaf(vv[j].w, vv[j].w, ss2);
        }
        ss2 += __shfl_xor(ss2, 1);
        ss2 += __shfl_xor(ss2, 2);          // k-row sumsq (4-lane group)
        // intra-norm * global norm (intra rows unit -> ||flat|| = sqrt(K) = 8)
        const float s1 = 0.125f / fmaxf(sqrtf(ss2), 1e-12f);
        float4* dst = (float4*)out + off4;
#pragma unroll
        for (int j = 0; j < 8; ++j) {
            float4 o = vv[j];
            o.x *= s1; o.y *= s1; o.z *= s1; o.w *= s1;
            dst[j] = o;
        }
    }
}

// Legacy finalize (atomic fallback path only)
__global__ __launch_bounds__(256)
void vlad_fin(const float* __restrict__ vacc, const float* __restrict__ asum,
              const float* __restrict__ cent, float* __restrict__ out, int npart)
{
    const int t   = threadIdx.x;
    const int b   = blockIdx.x;
    const int n   = b >> 3;
    const int oct = b & 7;
    const int k   = oct * 8 + (t >> 5);
    const int c   = t & 31;

    float a = 0.f;
    for (int g = 0; g < npart; ++g) a += asum[(size_t)g * (N_ * K_) + n * K_ + k];

    const size_t off4 = ((size_t)(n * K_ + k) * D_ >> 2) + c;
    float4 v = make_float4(0.f, 0.f, 0.f, 0.f);
    for (int g = 0; g < npart; ++g) {
        const float4 s = ((const float4*)vacc)[(size_t)g * ((size_t)N_ * K_ * D_ >> 2) + off4];
        v.x += s.x; v.y += s.y; v.z += s.z; v.w += s.w;
    }
    const float4 cc = ((const float4*)cent)[((size_t)k * D_ >> 2) + c];
    v.x -= a * cc.x; v.y -= a * cc.y; v.z -= a * cc.z; v.w -= a * cc.w;
    float ss = v.x * v.x + v.y * v.y + v.z * v.z + v.w * v.w;
    ss += __shfl_xor(ss, 1);
    ss += __shfl_xor(ss, 2);
    ss += __shfl_xor(ss, 4);
    ss += __shfl_xor(ss, 8);
    ss += __shfl_xor(ss, 16);
    const float s1 = 0.125f / fmaxf(sqrtf(ss), 1e-12f);
    float4 o;
    o.x = v.x * s1; o.y = v.y * s1; o.z = v.z * s1; o.w = v.w * s1;
    ((float4*)out)[off4] = o;
}

extern "C" void kernel_launch(void* const* d_in, const int* in_sizes, int n_in,
                              void* d_out, int out_size, void* d_ws, size_t ws_size,
                              hipStream_t stream)
{
    const float* x = (const float*)d_in[0];   // [N, D, H, W]
    const float* w = (const float*)d_in[1];   // [K, D]
    const float* c = (const float*)d_in[2];   // [K, D]
    float* out = (float*)d_out;               // [N, K*D]

    const size_t vs  = (size_t)N_ * K_ * D_;  // 524288
    const size_t as_ = (size_t)N_ * K_;       // 4096
    const size_t need = (NG_ * vs + NG_ * as_) * sizeof(float) + 256;  // ~25.4 MB
    float* vacc = (float*)d_ws;

    if (ws_size >= need) {
        float* ap = vacc + NG_ * vs;
        int* counters = (int*)(ap + NG_ * as_);
        hipMemsetAsync(counters, 0, N_ * sizeof(int), stream);
        vlad_main<<<dim3(N_ * NG_), dim3(256), 0, stream>>>(
            x, w, c, out, vacc, ap, counters, (int)vs, (int)as_);
    } else {
        float* ap = vacc + vs;
        hipMemsetAsync(d_ws, 0, (vs + as_) * sizeof(float), stream);
        vlad_main<<<dim3(N_ * NG_), dim3(256), 0, stream>>>(
            x, w, c, out, vacc, ap, nullptr, 0, 0);
        vlad_fin<<<dim3(N_ * 8), dim3(256), 0, stream>>>(vacc, ap, c, out, 1);
    }
}

// Round 11
// 42.469 us; speedup vs baseline: 4.5942x; 4.5942x over previous
//
#include <hip/hip_runtime.h>
#include <hip/hip_bf16.h>

#define N_   64
#define D_   128
#define L_   3136
#define K_   64
#define TL_  64
#define NG_  12     // pixel groups per image -> grid = 64*12 = 768 = 3 blocks/CU
// tiles per group: g==0 -> 5, else 4 (5 + 11*4 = 49 tiles of 64 pixels)
#define ASH  72     // As row stride in shorts (144B: 16B-aligned rows)

typedef short  short8  __attribute__((ext_vector_type(8)));
typedef short  short4v __attribute__((ext_vector_type(4)));
typedef float  f32x16  __attribute__((ext_vector_type(16)));

static __device__ __forceinline__ unsigned short f2bf(float f) {
    unsigned u = __float_as_uint(f);                       // RNE f32 -> bf16 bits
    return (unsigned short)((u + 0x7FFFu + ((u >> 16) & 1u)) >> 16);
}
static __device__ __forceinline__ float bf2f(short s) {
    return __uint_as_float(((unsigned)(unsigned short)s) << 16);
}
// packed RNE convert: lowers to v_cvt_pk_bf16_f32 (low16 = lo)
static __device__ __forceinline__ unsigned pk2(float lo, float hi) {
    __hip_bfloat162 b = __float22bfloat162_rn(make_float2(lo, hi));
    return *reinterpret_cast<unsigned*>(&b);
}

// Raw barrier: drains LDS (lgkmcnt) for write->barrier->read ordering, but
// does NOT drain vmcnt -- prefetch global loads stay in flight across it.
#define BARX() asm volatile("s_waitcnt lgkmcnt(0)\n\ts_barrier" ::: "memory")

// Full-MFMA fused NetVLAD main, software-pipelined (r9 structure + pk2).
// r10 lesson: NO device-scope fence / fused finalize -- __threadfence() on
// 8-XCD MI355X lowers to per-block L2 writebacks (10x regression). Separate
// fin kernel. pk2 converts keep VGPR at ~120 <= 128, so with 42KB LDS the HW
// fits 3 blocks/CU (12 waves) -- NG=12 makes the grid exactly 3/CU.
__global__ __launch_bounds__(256, 2)
void vlad_main(const float* __restrict__ x, const float* __restrict__ w,
               float* __restrict__ vout, float* __restrict__ aout,
               int vstride, int astride)   // vstride==0 => atomic accumulate path
{
    __shared__ __align__(16) short L1[TL_ * D_];   // [l][dk] bf16, swz ^((l&15)<<4), 16KB
    __shared__ __align__(16) short L2[D_ * TL_];   // [dk][l] bf16, swz ^((dk&7)<<4), 16KB
    __shared__ __align__(16) char  AsRaw[K_ * ASH * 2];  // bf16 a*inv [k][p], 9.2KB;
                                                         // rows 0..15 double as f32 red_ss[16][68]
    __shared__ float nrm_lds[TL_];
    __shared__ float dred[4][32];                  // softmax denominator exchange

    const int t    = threadIdx.x;
    const int lane = t & 63;
    const int wv   = __builtin_amdgcn_readfirstlane(t >> 6);  // 0..3
    const int n    = blockIdx.x / NG_;
    const int g    = blockIdx.x % NG_;
    const int tile0 = (g == 0) ? 0 : (4 * g + 1);
    const int ntile = (g == 0) ? 5 : 4;

    const int Mt = wv & 1;     // cluster-half (M) for both phases
    const int lg = lane >> 5;  // k-element group (0/1)
    const int lm = lane & 31;

    char* L1b = (char*)L1;
    char* L2b = (char*)L2;
    short* AsS = (short*)AsRaw;
    float (*red_ss)[68] = (float (*)[68])AsRaw;    // union: consumed before As written

    // ---- W fragments, loop-invariant, kept in 32 VGPRs ----
    short8 wf[8];
#pragma unroll
    for (int ks = 0; ks < 8; ++ks) {
        const float* wp = w + (size_t)(32 * Mt + lm) * D_ + 16 * ks + 8 * lg;
        const float4 wa = *(const float4*)wp;
        const float4 wb = *(const float4*)(wp + 4);
        union { unsigned u[4]; short8 s; } f;
        f.u[0] = pk2(wa.x, wa.y); f.u[1] = pk2(wa.z, wa.w);
        f.u[2] = pk2(wb.x, wb.y); f.u[3] = pk2(wb.z, wb.w);
        wf[ks] = f.s;
    }

    f32x16 acc0 = {0};   // V[k][d] C-frag, d-tile 2*(wv>>1)
    f32x16 acc1 = {0};   // d-tile 2*(wv>>1)+1
    float asum_acc = 0.f;

    const int q  = t >> 4;          // staging: d-rows 8q..8q+7
    const int l0 = (t & 15) * 4;    // staging: 4 pixels
    const float* xb = x + (size_t)n * D_ * L_;

    // ---- prologue: load tile 0 into registers ----
    float4 v[8];
    {
        const int p0 = tile0 * TL_;
#pragma unroll
        for (int r = 0; r < 8; ++r)
            v[r] = *(const float4*)(xb + (size_t)(8 * q + r) * L_ + p0 + l0);
    }

    for (int ti = 0; ti < ntile; ++ti) {
        // ---- stage current tile from v[]: sumsq + packed bf16 + L1 + L2 ----
#pragma unroll
        for (int j = 0; j < 4; ++j) {
            float s = 0.f;
#pragma unroll
            for (int r = 0; r < 8; ++r) {
                const float val = (&v[r].x)[j];
                s = fmaf(val, val, s);
            }
            red_ss[q][l0 + j] = s;
        }
#pragma unroll
        for (int j = 0; j < 4; ++j) {   // L1: per pixel, 8 consecutive dk (b128)
            const int l = l0 + j;
            union { unsigned u[4]; short8 s; } f;
            f.u[0] = pk2((&v[0].x)[j], (&v[1].x)[j]);
            f.u[1] = pk2((&v[2].x)[j], (&v[3].x)[j]);
            f.u[2] = pk2((&v[4].x)[j], (&v[5].x)[j]);
            f.u[3] = pk2((&v[6].x)[j], (&v[7].x)[j]);
            *(short8*)(L1b + l * 256 + ((16 * q) ^ ((l & 15) << 4))) = f.s;
        }
#pragma unroll
        for (int r = 0; r < 8; ++r) {   // L2: per d, 4 consecutive l (b64)
            const int d = 8 * q + r;
            union { unsigned u[2]; short4v s; } f;
            f.u[0] = pk2(v[r].x, v[r].y);
            f.u[1] = pk2(v[r].z, v[r].w);
            *(short4v*)(L2b + d * 128 + ((l0 * 2) ^ ((d & 7) << 4))) = f.s;
        }
        // ---- issue next tile's loads NOW (v[] just went dead); they stay
        //      in flight across the raw barriers below ----
        if (ti + 1 < ntile) {
            const int p0n = (tile0 + ti + 1) * TL_;
#pragma unroll
            for (int r = 0; r < 8; ++r)
                v[r] = *(const float4*)(xb + (size_t)(8 * q + r) * L_ + p0n + l0);
        }
        BARX();  // A: tile staged (red_ss/L1/L2 visible)
        // ---- per-pixel norm for asum (wave 0) ----
        if (t < TL_) {
            float ss = 0.f;
#pragma unroll
            for (int qq = 0; qq < 16; ++qq) ss += red_ss[qq][t];
            nrm_lds[t] = fmaxf(sqrtf(ss), 1e-12f);
        }
        // ---- phase 1: R = W * X (quadrant Mt x Nt), contraction dk=128 ----
        f32x16 r1 = {0};
        {
            const int l = 32 * (wv >> 1) + lm;   // pixel = col = lane&31
            const int rowoff = l * 256;
            const int swz = (l & 15) << 4;
            __builtin_amdgcn_s_setprio(1);
#pragma unroll
            for (int ks = 0; ks < 8; ++ks) {
                const short8 bfr = *(short8*)(L1b + rowoff + (((16 * ks + 8 * lg) * 2) ^ swz));
                r1 = __builtin_amdgcn_mfma_f32_32x32x16_bf16(wf[ks], bfr, r1, 0, 0, 0);
            }
            __builtin_amdgcn_s_setprio(0);
        }
        // ---- per-thread inv from red_ss ----
        const int myl = 32 * (wv >> 1) + lm;
        float ss16 = 0.f;
#pragma unroll
        for (int qq = 0; qq < 16; ++qq) ss16 += red_ss[qq][myl];
        const float invp = 1.f / fmaxf(sqrtf(ss16), 1e-12f);
        // ---- softmax over k (no max-sub; |logit*inv| <= ||w_k|| ~ 0.6) ----
        float e[16];
        float s = 0.f;
#pragma unroll
        for (int r = 0; r < 16; ++r) { e[r] = __expf(r1[r] * invp); s += e[r]; }
        s += __shfl_xor(s, 32);              // combine the two k-halves per pixel
        if (lane < 32) dred[wv][lm] = s;
        BARX();  // B: dred ready (and red_ss fully consumed)
        const float denom = dred[wv][lm] + dred[wv ^ 1][lm];   // cross-Mt partner
        const float sc = invp / denom;       // A_s = a * inv (agg uses raw X)
        {
            const int colp = 32 * (wv >> 1) + lm;
#pragma unroll
            for (int r = 0; r < 16; ++r) {   // bf16 store: 2B/lane, 2-way alias (free)
                const int k = 32 * Mt + (r & 3) + 8 * (r >> 2) + 4 * lg;
                AsS[k * ASH + colp] = (short)f2bf(e[r] * sc);
            }
        }
        BARX();  // C: A_s ready
        // ---- phase 2: V += A_s * X^T, contraction l=64 (af read direct) ----
        {
            short8 af[4];
            const char* arow = AsRaw + (size_t)(32 * Mt + lm) * (ASH * 2);
#pragma unroll
            for (int ks = 0; ks < 4; ++ks)
                af[ks] = *(const short8*)(arow + (16 * ks + 8 * lg) * 2);
            __builtin_amdgcn_s_setprio(1);
#pragma unroll
            for (int nt = 0; nt < 2; ++nt) {
                const int dk = 32 * (2 * (wv >> 1) + nt) + lm;  // d = col = lane&31
                const int rowoff = dk * 128;
                const int swz = (dk & 7) << 4;
                f32x16 a = (nt == 0) ? acc0 : acc1;
#pragma unroll
                for (int ks = 0; ks < 4; ++ks) {
                    const short8 bfr = *(short8*)(L2b + rowoff + (((16 * ks + 8 * lg) * 2) ^ swz));
                    a = __builtin_amdgcn_mfma_f32_32x32x16_bf16(af[ks], bfr, a, 0, 0, 0);
                }
                if (nt == 0) acc0 = a; else acc1 = a;
            }
            __builtin_amdgcn_s_setprio(0);
        }
        // ---- asum partial: asum[k] += sum_l A_s[k][l]*nrm[l] (bf16 reads) ----
        {
            const int k  = 16 * wv + (lane & 15);
            const int c4 = lane >> 4;                 // l-chunk 16*c4
            const char* ap = AsRaw + (size_t)k * (ASH * 2) + c4 * 32;
            const short8 a0 = *(const short8*)ap;
            const short8 a1 = *(const short8*)(ap + 16);
            float ps = 0.f;
#pragma unroll
            for (int i = 0; i < 8; ++i) {
                ps = fmaf(bf2f(a0[i]), nrm_lds[16 * c4 + i],     ps);
                ps = fmaf(bf2f(a1[i]), nrm_lds[16 * c4 + 8 + i], ps);
            }
            ps += __shfl_xor(ps, 16);
            ps += __shfl_xor(ps, 32);
            asum_acc += ps;
        }
        BARX();  // D: L1/L2/As/nrm consumers done (WAR for next staging)
    }
    // ---- commit: per-group slab (plain stores) or atomic fallback ----
    {
        const int dbase0 = 32 * (2 * (wv >> 1));
        float* vb = vstride ? (vout + (size_t)g * vstride) : vout;
#pragma unroll
        for (int r = 0; r < 16; ++r) {
            const int k = 32 * Mt + (r & 3) + 8 * (r >> 2) + 4 * lg;
            float* row = vb + ((size_t)n * K_ + k) * D_ + lm;
            if (vstride) {
                row[dbase0]      = acc0[r];
                row[dbase0 + 32] = acc1[r];
            } else {
                atomicAdd(&row[dbase0],      acc0[r]);
                atomicAdd(&row[dbase0 + 32], acc1[r]);
            }
        }
        if (lane < 16) {
            const int k = 16 * wv + lane;
            if (astride) aout[(size_t)g * astride + n * K_ + k] = asum_acc;
            else atomicAdd(&aout[n * K_ + k], asum_acc);
        }
    }
}

// Finalize, spread: one block per (n, k-octet). Sum slabs, subtract a*c,
// intra-normalize over d. Global norm = sqrt(K) = 8 exactly (unit rows).
__global__ __launch_bounds__(256)
void vlad_fin(const float* __restrict__ vacc, const float* __restrict__ asum,
              const float* __restrict__ cent, float* __restrict__ out, int npart)
{
    const int t   = threadIdx.x;
    const int b   = blockIdx.x;
    const int n   = b >> 3;
    const int oct = b & 7;
    const int k   = oct * 8 + (t >> 5);   // 8 k-rows per block
    const int c   = t & 31;               // float4 column; d = 4c

    float a = 0.f;
#pragma unroll 4
    for (int g = 0; g < npart; ++g) a += asum[(size_t)g * (N_ * K_) + n * K_ + k];

    const size_t off4 = ((size_t)(n * K_ + k) * D_ >> 2) + c;
    float4 v = make_float4(0.f, 0.f, 0.f, 0.f);
#pragma unroll 4
    for (int g = 0; g < npart; ++g) {
        const float4 s = ((const float4*)vacc)[(size_t)g * ((size_t)N_ * K_ * D_ >> 2) + off4];
        v.x += s.x; v.y += s.y; v.z += s.z; v.w += s.w;
    }
    const float4 cc = ((const float4*)cent)[((size_t)k * D_ >> 2) + c];
    v.x -= a * cc.x; v.y -= a * cc.y; v.z -= a * cc.z; v.w -= a * cc.w;
    float ss = v.x * v.x + v.y * v.y + v.z * v.z + v.w * v.w;
    ss += __shfl_xor(ss, 1);
    ss += __shfl_xor(ss, 2);
    ss += __shfl_xor(ss, 4);
    ss += __shfl_xor(ss, 8);
    ss += __shfl_xor(ss, 16);             // stays within the 32-lane row group
    const float s1 = 0.125f / fmaxf(sqrtf(ss), 1e-12f);   // intra-norm * 1/sqrt(K)
    float4 o;
    o.x = v.x * s1; o.y = v.y * s1; o.z = v.z * s1; o.w = v.w * s1;
    ((float4*)out)[off4] = o;
}

extern "C" void kernel_launch(void* const* d_in, const int* in_sizes, int n_in,
                              void* d_out, int out_size, void* d_ws, size_t ws_size,
                              hipStream_t stream)
{
    const float* x = (const float*)d_in[0];   // [N, D, H, W]
    const float* w = (const float*)d_in[1];   // [K, D]
    const float* c = (const float*)d_in[2];   // [K, D]
    float* out = (float*)d_out;               // [N, K*D]

    const size_t vs  = (size_t)N_ * K_ * D_;  // 524288
    const size_t as_ = (size_t)N_ * K_;       // 4096
    const size_t need = (NG_ * vs + NG_ * as_) * sizeof(float);  // ~25.4 MB
    float* vacc = (float*)d_ws;

    if (ws_size >= need) {
        float* ap = vacc + NG_ * vs;
        vlad_main<<<dim3(N_ * NG_), dim3(256), 0, stream>>>(x, w, vacc, ap,
                                                            (int)vs, (int)as_);
        vlad_fin<<<dim3(N_ * 8), dim3(256), 0, stream>>>(vacc, ap, c, out, NG_);
    } else {
        float* ap = vacc + vs;
        hipMemsetAsync(d_ws, 0, (vs + as_) * sizeof(float), stream);
        vlad_main<<<dim3(N_ * NG_), dim3(256), 0, stream>>>(x, w, vacc, ap, 0, 0);
        vlad_fin<<<dim3(N_ * 8), dim3(256), 0, stream>>>(vacc, ap, c, out, 1);
    }
}

// Round 12
// 38.955 us; speedup vs baseline: 5.0085x; 1.0902x over previous
//
#include <hip/hip_runtime.h>
#include <hip/hip_bf16.h>

#define N_   64
#define D_   128
#define L_   3136
#define K_   64
#define TL_  64
#define NG_  8      // pixel groups per image -> grid = 64*8 = 512 = 2 blocks/CU
// tiles per group: g==0 -> 7, else 6 (7 + 7*6 = 49 tiles of 64 pixels)
#define ASH  72     // As row stride in shorts (144B: 16B-aligned rows)

typedef short  short8  __attribute__((ext_vector_type(8)));
typedef short  short4v __attribute__((ext_vector_type(4)));
typedef float  f32x16  __attribute__((ext_vector_type(16)));

static __device__ __forceinline__ unsigned short f2bf(float f) {
    unsigned u = __float_as_uint(f);                       // RNE f32 -> bf16 bits
    return (unsigned short)((u + 0x7FFFu + ((u >> 16) & 1u)) >> 16);
}
static __device__ __forceinline__ float bf2f(short s) {
    return __uint_as_float(((unsigned)(unsigned short)s) << 16);
}
// packed RNE convert: lowers to v_cvt_pk_bf16_f32 (low16 = lo)
static __device__ __forceinline__ unsigned pk2(float lo, float hi) {
    __hip_bfloat162 b = __float22bfloat162_rn(make_float2(lo, hi));
    return *reinterpret_cast<unsigned*>(&b);
}

// Raw barrier: drains LDS (lgkmcnt) for write->barrier->read ordering, but
// does NOT drain vmcnt -- prefetch global loads stay in flight across it.
#define BARX() asm volatile("s_waitcnt lgkmcnt(0)\n\ts_barrier" ::: "memory")

// One full tile: stage from VBUF, re-issue VBUF for tile TNEXT (2-deep),
// then phase1 -> softmax -> As -> phase2 -> asum. All VBUF indexing static.
#define PROCESS(VBUF, TCUR, TNEXT)                                             \
    {                                                                          \
        /* stage: sumsq + packed bf16 -> L1 + L2 */                            \
        _Pragma("unroll")                                                      \
        for (int j = 0; j < 4; ++j) {                                          \
            float s = 0.f;                                                     \
            _Pragma("unroll")                                                  \
            for (int r = 0; r < 8; ++r) {                                      \
                const float val = (&VBUF[r].x)[j];                             \
                s = fmaf(val, val, s);                                         \
            }                                                                  \
            red_ss[q][l0 + j] = s;                                             \
        }                                                                      \
        _Pragma("unroll")                                                      \
        for (int j = 0; j < 4; ++j) {                                          \
            const int l = l0 + j;                                              \
            union { unsigned u[4]; short8 s; } f;                              \
            f.u[0] = pk2((&VBUF[0].x)[j], (&VBUF[1].x)[j]);                    \
            f.u[1] = pk2((&VBUF[2].x)[j], (&VBUF[3].x)[j]);                    \
            f.u[2] = pk2((&VBUF[4].x)[j], (&VBUF[5].x)[j]);                    \
            f.u[3] = pk2((&VBUF[6].x)[j], (&VBUF[7].x)[j]);                    \
            *(short8*)(L1b + l * 256 + ((16 * q) ^ ((l & 15) << 4))) = f.s;    \
        }                                                                      \
        _Pragma("unroll")                                                      \
        for (int r = 0; r < 8; ++r) {                                          \
            const int d = 8 * q + r;                                           \
            union { unsigned u[2]; short4v s; } f;                             \
            f.u[0] = pk2(VBUF[r].x, VBUF[r].y);                                \
            f.u[1] = pk2(VBUF[r].z, VBUF[r].w);                                \
            *(short4v*)(L2b + d * 128 + ((l0 * 2) ^ ((d & 7) << 4))) = f.s;    \
        }                                                                      \
        /* re-issue VBUF for tile TNEXT: in flight across all barriers */      \
        if ((TNEXT) < ntile) {                                                 \
            const int p0n = (tile0 + (TNEXT)) * TL_;                           \
            _Pragma("unroll")                                                  \
            for (int r = 0; r < 8; ++r)                                        \
                VBUF[r] = *(const float4*)(xb + (size_t)(8 * q + r) * L_ + p0n + l0); \
        }                                                                      \
        BARX();  /* A: tile staged */                                          \
        if (t < TL_) {                                                         \
            float ss = 0.f;                                                    \
            _Pragma("unroll")                                                  \
            for (int qq = 0; qq < 16; ++qq) ss += red_ss[qq][t];               \
            nrm_lds[t] = fmaxf(sqrtf(ss), 1e-12f);                             \
        }                                                                      \
        /* phase 1: R = W * X, contraction dk=128 */                           \
        f32x16 r1 = {0};                                                       \
        {                                                                      \
            const int l = 32 * (wv >> 1) + lm;                                 \
            const int rowoff = l * 256;                                        \
            const int swz = (l & 15) << 4;                                     \
            __builtin_amdgcn_s_setprio(1);                                     \
            _Pragma("unroll")                                                  \
            for (int ks = 0; ks < 8; ++ks) {                                   \
                const short8 bfr = *(short8*)(L1b + rowoff + (((16 * ks + 8 * lg) * 2) ^ swz)); \
                r1 = __builtin_amdgcn_mfma_f32_32x32x16_bf16(wf[ks], bfr, r1, 0, 0, 0); \
            }                                                                  \
            __builtin_amdgcn_s_setprio(0);                                     \
        }                                                                      \
        const int myl = 32 * (wv >> 1) + lm;                                   \
        float ss16 = 0.f;                                                      \
        _Pragma("unroll")                                                      \
        for (int qq = 0; qq < 16; ++qq) ss16 += red_ss[qq][myl];               \
        const float invp = 1.f / fmaxf(sqrtf(ss16), 1e-12f);                   \
        /* softmax over k (no max-sub; |logit*inv| <= ||w_k|| ~ 0.6) */        \
        float e[16];                                                           \
        float s = 0.f;                                                         \
        _Pragma("unroll")                                                      \
        for (int r = 0; r < 16; ++r) { e[r] = __expf(r1[r] * invp); s += e[r]; } \
        s += __shfl_xor(s, 32);                                                \
        if (lane < 32) dred[wv][lm] = s;                                       \
        BARX();  /* B: dred ready; red_ss consumed */                          \
        const float denom = dred[wv][lm] + dred[wv ^ 1][lm];                   \
        const float sc = invp / denom;                                         \
        {                                                                      \
            const int colp = 32 * (wv >> 1) + lm;                              \
            _Pragma("unroll")                                                  \
            for (int r = 0; r < 16; ++r) {                                     \
                const int k = 32 * Mt + (r & 3) + 8 * (r >> 2) + 4 * lg;       \
                AsS[k * ASH + colp] = (short)f2bf(e[r] * sc);                  \
            }                                                                  \
        }                                                                      \
        BARX();  /* C: A_s ready */                                            \
        /* phase 2: V += A_s * X^T, contraction l=64 */                        \
        {                                                                      \
            short8 af[4];                                                      \
            const char* arow = AsRaw + (size_t)(32 * Mt + lm) * (ASH * 2);     \
            _Pragma("unroll")                                                  \
            for (int ks = 0; ks < 4; ++ks)                                     \
                af[ks] = *(const short8*)(arow + (16 * ks + 8 * lg) * 2);      \
            __builtin_amdgcn_s_setprio(1);                                     \
            _Pragma("unroll")                                                  \
            for (int nt = 0; nt < 2; ++nt) {                                   \
                const int dk = 32 * (2 * (wv >> 1) + nt) + lm;                 \
                const int rowoff = dk * 128;                                   \
                const int swz = (dk & 7) << 4;                                 \
                f32x16 a = (nt == 0) ? acc0 : acc1;                            \
                _Pragma("unroll")                                              \
                for (int ks = 0; ks < 4; ++ks) {                               \
                    const short8 bfr = *(short8*)(L2b + rowoff + (((16 * ks + 8 * lg) * 2) ^ swz)); \
                    a = __builtin_amdgcn_mfma_f32_32x32x16_bf16(af[ks], bfr, a, 0, 0, 0); \
                }                                                              \
                if (nt == 0) acc0 = a; else acc1 = a;                          \
            }                                                                  \
            __builtin_amdgcn_s_setprio(0);                                     \
        }                                                                      \
        /* asum partial */                                                     \
        {                                                                      \
            const int k  = 16 * wv + (lane & 15);                              \
            const int c4 = lane >> 4;                                          \
            const char* ap = AsRaw + (size_t)k * (ASH * 2) + c4 * 32;          \
            const short8 a0 = *(const short8*)ap;                              \
            const short8 a1 = *(const short8*)(ap + 16);                       \
            float ps = 0.f;                                                    \
            _Pragma("unroll")                                                  \
            for (int i = 0; i < 8; ++i) {                                      \
                ps = fmaf(bf2f(a0[i]), nrm_lds[16 * c4 + i],     ps);          \
                ps = fmaf(bf2f(a1[i]), nrm_lds[16 * c4 + 8 + i], ps);          \
            }                                                                  \
            ps += __shfl_xor(ps, 16);                                          \
            ps += __shfl_xor(ps, 32);                                          \
            asum_acc += ps;                                                    \
        }                                                                      \
        BARX();  /* D: WAR for next staging */                                 \
    }

// Full-MFMA fused NetVLAD main, 2-deep software pipeline.
// r11 lesson: main is BW-starved (stream 16.4us/CU floor vs ~28us observed);
// 1-deep prefetch covers only half the per-tile load time at 2 blocks/CU.
// Two register buffers (va/vb), statically alternated (rule #20), give a
// 2-tile load-to-use distance. NG=8: fewer exposed prologues than NG=12.
__global__ __launch_bounds__(256, 2)
void vlad_main(const float* __restrict__ x, const float* __restrict__ w,
               float* __restrict__ vout, float* __restrict__ aout,
               int vstride, int astride)   // vstride==0 => atomic accumulate path
{
    __shared__ __align__(16) short L1[TL_ * D_];   // [l][dk] bf16, swz ^((l&15)<<4), 16KB
    __shared__ __align__(16) short L2[D_ * TL_];   // [dk][l] bf16, swz ^((dk&7)<<4), 16KB
    __shared__ __align__(16) char  AsRaw[K_ * ASH * 2];  // bf16 a*inv [k][p], 9.2KB;
                                                         // rows 0..15 double as f32 red_ss[16][68]
    __shared__ float nrm_lds[TL_];
    __shared__ float dred[4][32];                  // softmax denominator exchange

    const int t    = threadIdx.x;
    const int lane = t & 63;
    const int wv   = __builtin_amdgcn_readfirstlane(t >> 6);  // 0..3
    const int n    = blockIdx.x / NG_;
    const int g    = blockIdx.x % NG_;
    const int tile0 = (g == 0) ? 0 : (7 + 6 * (g - 1));
    const int ntile = (g == 0) ? 7 : 6;

    const int Mt = wv & 1;     // cluster-half (M) for both phases
    const int lg = lane >> 5;  // k-element group (0/1)
    const int lm = lane & 31;

    char* L1b = (char*)L1;
    char* L2b = (char*)L2;
    short* AsS = (short*)AsRaw;
    float (*red_ss)[68] = (float (*)[68])AsRaw;    // union: consumed before As written

    // ---- W fragments, loop-invariant, kept in 32 VGPRs ----
    short8 wf[8];
#pragma unroll
    for (int ks = 0; ks < 8; ++ks) {
        const float* wp = w + (size_t)(32 * Mt + lm) * D_ + 16 * ks + 8 * lg;
        const float4 wa = *(const float4*)wp;
        const float4 wb = *(const float4*)(wp + 4);
        union { unsigned u[4]; short8 s; } f;
        f.u[0] = pk2(wa.x, wa.y); f.u[1] = pk2(wa.z, wa.w);
        f.u[2] = pk2(wb.x, wb.y); f.u[3] = pk2(wb.z, wb.w);
        wf[ks] = f.s;
    }

    f32x16 acc0 = {0};   // V[k][d] C-frag, d-tile 2*(wv>>1)
    f32x16 acc1 = {0};   // d-tile 2*(wv>>1)+1
    float asum_acc = 0.f;

    const int q  = t >> 4;          // staging: d-rows 8q..8q+7
    const int l0 = (t & 15) * 4;    // staging: 4 pixels
    const float* xb = x + (size_t)n * D_ * L_;

    // ---- prologue: load tiles 0 and 1 into the two buffers ----
    float4 va[8], vb[8];
    {
        const int p0 = tile0 * TL_;
#pragma unroll
        for (int r = 0; r < 8; ++r)
            va[r] = *(const float4*)(xb + (size_t)(8 * q + r) * L_ + p0 + l0);
        const int p1 = (tile0 + 1) * TL_;   // ntile >= 6 always
#pragma unroll
        for (int r = 0; r < 8; ++r)
            vb[r] = *(const float4*)(xb + (size_t)(8 * q + r) * L_ + p1 + l0);
    }

    for (int tp = 0; tp < ntile; tp += 2) {
        PROCESS(va, tp, tp + 2)
        if (tp + 1 < ntile) {
            PROCESS(vb, tp + 1, tp + 3)
        }
    }

    // ---- commit: per-group slab (plain stores) or atomic fallback ----
    {
        const int dbase0 = 32 * (2 * (wv >> 1));
        float* vb2 = vstride ? (vout + (size_t)g * vstride) : vout;
#pragma unroll
        for (int r = 0; r < 16; ++r) {
            const int k = 32 * Mt + (r & 3) + 8 * (r >> 2) + 4 * lg;
            float* row = vb2 + ((size_t)n * K_ + k) * D_ + lm;
            if (vstride) {
                row[dbase0]      = acc0[r];
                row[dbase0 + 32] = acc1[r];
            } else {
                atomicAdd(&row[dbase0],      acc0[r]);
                atomicAdd(&row[dbase0 + 32], acc1[r]);
            }
        }
        if (lane < 16) {
            const int k = 16 * wv + lane;
            if (astride) aout[(size_t)g * astride + n * K_ + k] = asum_acc;
            else atomicAdd(&aout[n * K_ + k], asum_acc);
        }
    }
}

// Finalize, spread: one block per (n, k-octet). Sum slabs, subtract a*c,
// intra-normalize over d. Global norm = sqrt(K) = 8 exactly (unit rows).
__global__ __launch_bounds__(256)
void vlad_fin(const float* __restrict__ vacc, const float* __restrict__ asum,
              const float* __restrict__ cent, float* __restrict__ out, int npart)
{
    const int t   = threadIdx.x;
    const int b   = blockIdx.x;
    const int n   = b >> 3;
    const int oct = b & 7;
    const int k   = oct * 8 + (t >> 5);   // 8 k-rows per block
    const int c   = t & 31;               // float4 column; d = 4c

    float a = 0.f;
#pragma unroll 4
    for (int g = 0; g < npart; ++g) a += asum[(size_t)g * (N_ * K_) + n * K_ + k];

    const size_t off4 = ((size_t)(n * K_ + k) * D_ >> 2) + c;
    float4 v = make_float4(0.f, 0.f, 0.f, 0.f);
#pragma unroll 4
    for (int g = 0; g < npart; ++g) {
        const float4 s = ((const float4*)vacc)[(size_t)g * ((size_t)N_ * K_ * D_ >> 2) + off4];
        v.x += s.x; v.y += s.y; v.z += s.z; v.w += s.w;
    }
    const float4 cc = ((const float4*)cent)[((size_t)k * D_ >> 2) + c];
    v.x -= a * cc.x; v.y -= a * cc.y; v.z -= a * cc.z; v.w -= a * cc.w;
    float ss = v.x * v.x + v.y * v.y + v.z * v.z + v.w * v.w;
    ss += __shfl_xor(ss, 1);
    ss += __shfl_xor(ss, 2);
    ss += __shfl_xor(ss, 4);
    ss += __shfl_xor(ss, 8);
    ss += __shfl_xor(ss, 16);             // stays within the 32-lane row group
    const float s1 = 0.125f / fmaxf(sqrtf(ss), 1e-12f);   // intra-norm * 1/sqrt(K)
    float4 o;
    o.x = v.x * s1; o.y = v.y * s1; o.z = v.z * s1; o.w = v.w * s1;
    ((float4*)out)[off4] = o;
}

extern "C" void kernel_launch(void* const* d_in, const int* in_sizes, int n_in,
                              void* d_out, int out_size, void* d_ws, size_t ws_size,
                              hipStream_t stream)
{
    const float* x = (const float*)d_in[0];   // [N, D, H, W]
    const float* w = (const float*)d_in[1];   // [K, D]
    const float* c = (const float*)d_in[2];   // [K, D]
    float* out = (float*)d_out;               // [N, K*D]

    const size_t vs  = (size_t)N_ * K_ * D_;  // 524288
    const size_t as_ = (size_t)N_ * K_;       // 4096
    const size_t need = (NG_ * vs + NG_ * as_) * sizeof(float);  // ~16.9 MB
    float* vacc = (float*)d_ws;

    if (ws_size >= need) {
        float* ap = vacc + NG_ * vs;
        vlad_main<<<dim3(N_ * NG_), dim3(256), 0, stream>>>(x, w, vacc, ap,
                                                            (int)vs, (int)as_);
        vlad_fin<<<dim3(N_ * 8), dim3(256), 0, stream>>>(vacc, ap, c, out, NG_);
    } else {
        float* ap = vacc + vs;
        hipMemsetAsync(d_ws, 0, (vs + as_) * sizeof(float), stream);
        vlad_main<<<dim3(N_ * NG_), dim3(256), 0, stream>>>(x, w, vacc, ap, 0, 0);
        vlad_fin<<<dim3(N_ * 8), dim3(256), 0, stream>>>(vacc, ap, c, out, 1);
    }
}

// Round 13
// 35.204 us; speedup vs baseline: 5.5423x; 1.1066x over previous
//
#include <hip/hip_runtime.h>
#include <hip/hip_bf16.h>

#define N_   64
#define D_   128
#define L_   3136
#define K_   64
#define TL_  64
#define NG_  8      // pixel groups per image -> grid = 64*8 = 512 = 2 blocks/CU
// tiles per group: g==0 -> 7, else 6 (7 + 7*6 = 49 tiles of 64 pixels)
#define ASH  72     // As row stride in shorts (144B: 16B-aligned rows)
#define VSLAB ((size_t)N_ * K_ * D_)   // bf16 elements per V slab

typedef short  short8  __attribute__((ext_vector_type(8)));
typedef short  short4v __attribute__((ext_vector_type(4)));
typedef float  f32x16  __attribute__((ext_vector_type(16)));

static __device__ __forceinline__ unsigned short f2bf(float f) {
    unsigned u = __float_as_uint(f);                       // RNE f32 -> bf16 bits
    return (unsigned short)((u + 0x7FFFu + ((u >> 16) & 1u)) >> 16);
}
static __device__ __forceinline__ float bf2f(short s) {
    return __uint_as_float(((unsigned)(unsigned short)s) << 16);
}
// packed RNE convert: lowers to v_cvt_pk_bf16_f32 (low16 = lo)
static __device__ __forceinline__ unsigned pk2(float lo, float hi) {
    __hip_bfloat162 b = __float22bfloat162_rn(make_float2(lo, hi));
    return *reinterpret_cast<unsigned*>(&b);
}

// Raw barrier: drains LDS (lgkmcnt) for write->barrier->read ordering, but
// does NOT drain vmcnt -- prefetch global loads stay in flight across it.
#define BARX() asm volatile("s_waitcnt lgkmcnt(0)\n\ts_barrier" ::: "memory")

// Full-MFMA fused NetVLAD main (r9 skeleton + serial-path diet):
//  - sumsq via 2x shfl_xor -> red4[4][64]; inv/nrm consumers read 4 b32 not 16
//  - asum nrm reads as 4x b128
//  - As stores via pk2+shift (16 VALU vs 48)
//  - V slabs in bf16 (halves fin round-trip; asum stays f32)
__global__ __launch_bounds__(256, 2)
void vlad_main(const float* __restrict__ x, const float* __restrict__ w,
               short* __restrict__ vout, float* __restrict__ aout)
{
    __shared__ __align__(16) short L1[TL_ * D_];   // [l][dk] bf16, swz ^((l&15)<<4), 16KB
    __shared__ __align__(16) short L2[D_ * TL_];   // [dk][l] bf16, swz ^((dk&7)<<4), 16KB
    __shared__ __align__(16) char  AsRaw[K_ * ASH * 2];  // bf16 a*inv [k][p], 9.2KB
    __shared__ __align__(16) float red4[4][TL_];   // per-wave 32-d sumsq partials, 1KB
    __shared__ __align__(16) float nrm_lds[TL_];
    __shared__ float dred[4][32];                  // softmax denominator exchange

    const int t    = threadIdx.x;
    const int lane = t & 63;
    const int wv   = __builtin_amdgcn_readfirstlane(t >> 6);  // 0..3
    const int n    = blockIdx.x / NG_;
    const int g    = blockIdx.x % NG_;
    const int tile0 = (g == 0) ? 0 : (7 + 6 * (g - 1));
    const int ntile = (g == 0) ? 7 : 6;

    const int Mt = wv & 1;     // cluster-half (M) for both phases
    const int lg = lane >> 5;  // k-element group (0/1)
    const int lm = lane & 31;

    char* L1b = (char*)L1;
    char* L2b = (char*)L2;
    short* AsS = (short*)AsRaw;

    // ---- W fragments, loop-invariant, kept in 32 VGPRs ----
    short8 wf[8];
#pragma unroll
    for (int ks = 0; ks < 8; ++ks) {
        const float* wp = w + (size_t)(32 * Mt + lm) * D_ + 16 * ks + 8 * lg;
        const float4 wa = *(const float4*)wp;
        const float4 wb = *(const float4*)(wp + 4);
        union { unsigned u[4]; short8 s; } f;
        f.u[0] = pk2(wa.x, wa.y); f.u[1] = pk2(wa.z, wa.w);
        f.u[2] = pk2(wb.x, wb.y); f.u[3] = pk2(wb.z, wb.w);
        wf[ks] = f.s;
    }

    f32x16 acc0 = {0};   // V[k][d] C-frag, d-tile 2*(wv>>1)
    f32x16 acc1 = {0};   // d-tile 2*(wv>>1)+1
    float asum_acc = 0.f;

    const int q  = t >> 4;          // staging: d-rows 8q..8q+7
    const int l0 = (t & 15) * 4;    // staging: 4 pixels
    const float* xb = x + (size_t)n * D_ * L_;

    // ---- prologue: load tile 0 into registers ----
    float4 v[8];
    {
        const int p0 = tile0 * TL_;
#pragma unroll
        for (int r = 0; r < 8; ++r)
            v[r] = *(const float4*)(xb + (size_t)(8 * q + r) * L_ + p0 + l0);
    }

    for (int ti = 0; ti < ntile; ++ti) {
        // ---- sumsq partials (8 d each) -> wave-level shfl reduce (32 d) ----
        float s4[4];
#pragma unroll
        for (int j = 0; j < 4; ++j) {
            float s = 0.f;
#pragma unroll
            for (int r = 0; r < 8; ++r) {
                const float val = (&v[r].x)[j];
                s = fmaf(val, val, s);
            }
            s4[j] = s;
        }
#pragma unroll
        for (int j = 0; j < 4; ++j) {   // combine this wave's 4 q-rows
            s4[j] += __shfl_xor(s4[j], 16);
            s4[j] += __shfl_xor(s4[j], 32);
        }
        if (lane < 16)                  // one float4 per pixel-group per wave
            *(float4*)&red4[wv][lane * 4] = make_float4(s4[0], s4[1], s4[2], s4[3]);
        // ---- packed bf16 converts -> L1 + L2 ----
#pragma unroll
        for (int j = 0; j < 4; ++j) {   // L1: per pixel, 8 consecutive dk (b128)
            const int l = l0 + j;
            union { unsigned u[4]; short8 s; } f;
            f.u[0] = pk2((&v[0].x)[j], (&v[1].x)[j]);
            f.u[1] = pk2((&v[2].x)[j], (&v[3].x)[j]);
            f.u[2] = pk2((&v[4].x)[j], (&v[5].x)[j]);
            f.u[3] = pk2((&v[6].x)[j], (&v[7].x)[j]);
            *(short8*)(L1b + l * 256 + ((16 * q) ^ ((l & 15) << 4))) = f.s;
        }
#pragma unroll
        for (int r = 0; r < 8; ++r) {   // L2: per d, 4 consecutive l (b64)
            const int d = 8 * q + r;
            union { unsigned u[2]; short4v s; } f;
            f.u[0] = pk2(v[r].x, v[r].y);
            f.u[1] = pk2(v[r].z, v[r].w);
            *(short4v*)(L2b + d * 128 + ((l0 * 2) ^ ((d & 7) << 4))) = f.s;
        }
        // ---- issue next tile's loads NOW (v[] dead); in flight across barriers ----
        if (ti + 1 < ntile) {
            const int p0n = (tile0 + ti + 1) * TL_;
#pragma unroll
            for (int r = 0; r < 8; ++r)
                v[r] = *(const float4*)(xb + (size_t)(8 * q + r) * L_ + p0n + l0);
        }
        BARX();  // A: tile staged (red4/L1/L2 visible)
        // ---- per-pixel norm for asum (wave 0): 4 reads ----
        if (t < TL_) {
            const float ss = red4[0][t] + red4[1][t] + red4[2][t] + red4[3][t];
            nrm_lds[t] = fmaxf(sqrtf(ss), 1e-12f);
        }
        // ---- phase 1: R = W * X (quadrant Mt x Nt), contraction dk=128 ----
        f32x16 r1 = {0};
        {
            const int l = 32 * (wv >> 1) + lm;   // pixel = col = lane&31
            const int rowoff = l * 256;
            const int swz = (l & 15) << 4;
            __builtin_amdgcn_s_setprio(1);
#pragma unroll
            for (int ks = 0; ks < 8; ++ks) {
                const short8 bfr = *(short8*)(L1b + rowoff + (((16 * ks + 8 * lg) * 2) ^ swz));
                r1 = __builtin_amdgcn_mfma_f32_32x32x16_bf16(wf[ks], bfr, r1, 0, 0, 0);
            }
            __builtin_amdgcn_s_setprio(0);
        }
        // ---- per-thread inv: 4 reads ----
        const int myl = 32 * (wv >> 1) + lm;
        const float ss16 = red4[0][myl] + red4[1][myl] + red4[2][myl] + red4[3][myl];
        const float invp = 1.f / fmaxf(sqrtf(ss16), 1e-12f);
        // ---- softmax over k (no max-sub; |logit*inv| <= ||w_k|| ~ 0.6) ----
        float e[16];
        float s = 0.f;
#pragma unroll
        for (int r = 0; r < 16; ++r) { e[r] = __expf(r1[r] * invp); s += e[r]; }
        s += __shfl_xor(s, 32);              // combine the two k-halves per pixel
        if (lane < 32) dred[wv][lm] = s;
        BARX();  // B: dred ready (red4 consumed)
        const float denom = dred[wv][lm] + dred[wv ^ 1][lm];   // cross-Mt partner
        const float sc = invp / denom;       // A_s = a * inv (agg uses raw X)
        {
            const int colp = 32 * (wv >> 1) + lm;
#pragma unroll
            for (int rr = 0; rr < 8; ++rr) { // pairs r=2rr,2rr+1 -> k,k+1 (same col)
                const int r = 2 * rr;
                const int k = 32 * Mt + (r & 3) + 8 * (r >> 2) + 4 * lg;
                const unsigned u = pk2(e[r] * sc, e[r + 1] * sc);
                AsS[k * ASH + colp]       = (short)u;
                AsS[(k + 1) * ASH + colp] = (short)(u >> 16);
            }
        }
        BARX();  // C: A_s ready
        // ---- phase 2: V += A_s * X^T, contraction l=64 (af read direct) ----
        {
            short8 af[4];
            const char* arow = AsRaw + (size_t)(32 * Mt + lm) * (ASH * 2);
#pragma unroll
            for (int ks = 0; ks < 4; ++ks)
                af[ks] = *(const short8*)(arow + (16 * ks + 8 * lg) * 2);
            __builtin_amdgcn_s_setprio(1);
#pragma unroll
            for (int nt = 0; nt < 2; ++nt) {
                const int dk = 32 * (2 * (wv >> 1) + nt) + lm;  // d = col = lane&31
                const int rowoff = dk * 128;
                const int swz = (dk & 7) << 4;
                f32x16 a = (nt == 0) ? acc0 : acc1;
#pragma unroll
                for (int ks = 0; ks < 4; ++ks) {
                    const short8 bfr = *(short8*)(L2b + rowoff + (((16 * ks + 8 * lg) * 2) ^ swz));
                    a = __builtin_amdgcn_mfma_f32_32x32x16_bf16(af[ks], bfr, a, 0, 0, 0);
                }
                if (nt == 0) acc0 = a; else acc1 = a;
            }
            __builtin_amdgcn_s_setprio(0);
        }
        // ---- asum partial: asum[k] += sum_l A_s[k][l]*nrm[l] (vector reads) ----
        {
            const int k  = 16 * wv + (lane & 15);
            const int c4 = lane >> 4;                 // l-chunk 16*c4
            const char* ap = AsRaw + (size_t)k * (ASH * 2) + c4 * 32;
            const short8 a0 = *(const short8*)ap;
            const short8 a1 = *(const short8*)(ap + 16);
            const float4* np = (const float4*)&nrm_lds[16 * c4];
            const float4 n0 = np[0], n1 = np[1], n2 = np[2], n3 = np[3];
            float ps = 0.f;
            ps = fmaf(bf2f(a0[0]), n0.x, ps); ps = fmaf(bf2f(a0[1]), n0.y, ps);
            ps = fmaf(bf2f(a0[2]), n0.z, ps); ps = fmaf(bf2f(a0[3]), n0.w, ps);
            ps = fmaf(bf2f(a0[4]), n1.x, ps); ps = fmaf(bf2f(a0[5]), n1.y, ps);
            ps = fmaf(bf2f(a0[6]), n1.z, ps); ps = fmaf(bf2f(a0[7]), n1.w, ps);
            ps = fmaf(bf2f(a1[0]), n2.x, ps); ps = fmaf(bf2f(a1[1]), n2.y, ps);
            ps = fmaf(bf2f(a1[2]), n2.z, ps); ps = fmaf(bf2f(a1[3]), n2.w, ps);
            ps = fmaf(bf2f(a1[4]), n3.x, ps); ps = fmaf(bf2f(a1[5]), n3.y, ps);
            ps = fmaf(bf2f(a1[6]), n3.z, ps); ps = fmaf(bf2f(a1[7]), n3.w, ps);
            ps += __shfl_xor(ps, 16);
            ps += __shfl_xor(ps, 32);
            asum_acc += ps;
        }
        BARX();  // D: L1/L2/As/nrm consumers done (WAR for next staging)
    }
    // ---- commit: per-group bf16 slab (plain stores) ----
    {
        const int dbase0 = 32 * (2 * (wv >> 1));
        short* vb2 = vout + (size_t)g * VSLAB;
#pragma unroll
        for (int r = 0; r < 16; ++r) {
            const int k = 32 * Mt + (r & 3) + 8 * (r >> 2) + 4 * lg;
            short* row = vb2 + ((size_t)n * K_ + k) * D_ + lm;
            const unsigned u = pk2(acc0[r], acc1[r]);
            row[dbase0]      = (short)u;
            row[dbase0 + 32] = (short)(u >> 16);
        }
        if (lane < 16) {
            const int k = 16 * wv + lane;
            aout[(size_t)g * (N_ * K_) + n * K_ + k] = asum_acc;
        }
    }
}

// Finalize, spread: one block per (n, k-octet). Sum bf16 slabs, subtract a*c,
// intra-normalize over d. Global norm = sqrt(K) = 8 exactly (unit rows).
__global__ __launch_bounds__(256)
void vlad_fin(const short* __restrict__ vacc, const float* __restrict__ asum,
              const float* __restrict__ cent, float* __restrict__ out)
{
    const int t   = threadIdx.x;
    const int b   = blockIdx.x;
    const int n   = b >> 3;
    const int oct = b & 7;
    const int k   = oct * 8 + (t >> 5);   // 8 k-rows per block
    const int c   = t & 31;               // float4 column; d = 4c

    float a = 0.f;
#pragma unroll
    for (int g = 0; g < NG_; ++g) a += asum[(size_t)g * (N_ * K_) + n * K_ + k];

    const size_t roff = ((size_t)(n * K_ + k)) * D_ + c * 4;
    float4 v = make_float4(0.f, 0.f, 0.f, 0.f);
#pragma unroll
    for (int g = 0; g < NG_; ++g) {
        const short4v s = *(const short4v*)(vacc + (size_t)g * VSLAB + roff);
        v.x += bf2f(s[0]); v.y += bf2f(s[1]);
        v.z += bf2f(s[2]); v.w += bf2f(s[3]);
    }
    const float4 cc = ((const float4*)cent)[((size_t)k * D_ >> 2) + c];
    v.x -= a * cc.x; v.y -= a * cc.y; v.z -= a * cc.z; v.w -= a * cc.w;
    float ss = v.x * v.x + v.y * v.y + v.z * v.z + v.w * v.w;
    ss += __shfl_xor(ss, 1);
    ss += __shfl_xor(ss, 2);
    ss += __shfl_xor(ss, 4);
    ss += __shfl_xor(ss, 8);
    ss += __shfl_xor(ss, 16);             // stays within the 32-lane row group
    const float s1 = 0.125f / fmaxf(sqrtf(ss), 1e-12f);   // intra-norm * 1/sqrt(K)
    float4 o;
    o.x = v.x * s1; o.y = v.y * s1; o.z = v.z * s1; o.w = v.w * s1;
    *(float4*)(out + roff) = o;
}

extern "C" void kernel_launch(void* const* d_in, const int* in_sizes, int n_in,
                              void* d_out, int out_size, void* d_ws, size_t ws_size,
                              hipStream_t stream)
{
    const float* x = (const float*)d_in[0];   // [N, D, H, W]
    const float* w = (const float*)d_in[1];   // [K, D]
    const float* c = (const float*)d_in[2];   // [K, D]
    float* out = (float*)d_out;               // [N, K*D]

    short* vacc = (short*)d_ws;                          // NG bf16 V slabs (8.4MB)
    float* ap   = (float*)(vacc + NG_ * VSLAB);          // NG f32 asum slabs (131KB)
    // ws_size observed ~392MB >> 8.6MB needed; plain stores, no zero-init required.

    vlad_main<<<dim3(N_ * NG_), dim3(256), 0, stream>>>(x, w, vacc, ap);
    vlad_fin<<<dim3(N_ * 8), dim3(256), 0, stream>>>(vacc, ap, c, out);
}

// Round 14
// 34.411 us; speedup vs baseline: 5.6700x; 1.0231x over previous
//
#include <hip/hip_runtime.h>
#include <hip/hip_bf16.h>

#define N_   64
#define D_   128
#define L_   3136
#define K_   64
#define TL_  64
#define NG_  8      // pixel groups per image -> grid = 64*8 = 512 = 2 blocks/CU
// tiles per group: g==0 -> 7, else 6 (7 + 7*6 = 49 tiles of 64 pixels)
#define ASH  72     // As row stride in shorts (144B: 16B-aligned rows)
#define VSLAB ((size_t)N_ * K_ * D_)   // bf16 elements per V slab

typedef short  short8  __attribute__((ext_vector_type(8)));
typedef short  short4v __attribute__((ext_vector_type(4)));
typedef float  f32x16  __attribute__((ext_vector_type(16)));

static __device__ __forceinline__ float bf2f(short s) {
    return __uint_as_float(((unsigned)(unsigned short)s) << 16);
}
// packed RNE convert: lowers to v_cvt_pk_bf16_f32 (low16 = lo)
static __device__ __forceinline__ unsigned pk2(float lo, float hi) {
    __hip_bfloat162 b = __float22bfloat162_rn(make_float2(lo, hi));
    return *reinterpret_cast<unsigned*>(&b);
}

// Raw barrier: drains LDS (lgkmcnt) for write->barrier->read ordering, but
// does NOT drain vmcnt -- prefetch global loads stay in flight across it.
#define BARX() asm volatile("s_waitcnt lgkmcnt(0)\n\ts_barrier" ::: "memory")

// One tile, staged into LDS buffer (L1BUF/L2BUF alternate per tile parity).
// Barriers: A (staging RAW), B (dred RAW), C (As RAW). No D: the WAR that D
// protected (next staging vs this tile's readers) is gone -- next staging
// writes the OTHER buffer, and the buffer is only rewritten 2 tiles later,
// behind B(i), C(i), A(i+1).
#define PROCESS(TCUR, L1BUF, L2BUF)                                            \
    {                                                                          \
        const char* L1b = (const char*)(L1BUF);                                \
        const char* L2b = (const char*)(L2BUF);                                \
        /* sumsq partials (8 d each) -> wave shfl reduce (32 d) -> red4 */     \
        float s4[4];                                                           \
        _Pragma("unroll")                                                      \
        for (int j = 0; j < 4; ++j) {                                          \
            float s = 0.f;                                                     \
            _Pragma("unroll")                                                  \
            for (int r = 0; r < 8; ++r) {                                      \
                const float val = (&v[r].x)[j];                                \
                s = fmaf(val, val, s);                                         \
            }                                                                  \
            s4[j] = s;                                                         \
        }                                                                      \
        _Pragma("unroll")                                                      \
        for (int j = 0; j < 4; ++j) {                                          \
            s4[j] += __shfl_xor(s4[j], 16);                                    \
            s4[j] += __shfl_xor(s4[j], 32);                                    \
        }                                                                      \
        if (lane < 16)                                                         \
            *(float4*)&red4[wv][lane * 4] = make_float4(s4[0], s4[1], s4[2], s4[3]); \
        /* packed bf16 -> L1 + L2 (current parity buffer) */                   \
        _Pragma("unroll")                                                      \
        for (int j = 0; j < 4; ++j) {                                          \
            const int l = l0 + j;                                              \
            union { unsigned u[4]; short8 s; } f;                              \
            f.u[0] = pk2((&v[0].x)[j], (&v[1].x)[j]);                          \
            f.u[1] = pk2((&v[2].x)[j], (&v[3].x)[j]);                          \
            f.u[2] = pk2((&v[4].x)[j], (&v[5].x)[j]);                          \
            f.u[3] = pk2((&v[6].x)[j], (&v[7].x)[j]);                          \
            *(short8*)((char*)L1b + l * 256 + ((16 * q) ^ ((l & 15) << 4))) = f.s; \
        }                                                                      \
        _Pragma("unroll")                                                      \
        for (int r = 0; r < 8; ++r) {                                          \
            const int d = 8 * q + r;                                           \
            union { unsigned u[2]; short4v s; } f;                             \
            f.u[0] = pk2(v[r].x, v[r].y);                                      \
            f.u[1] = pk2(v[r].z, v[r].w);                                      \
            *(short4v*)((char*)L2b + d * 128 + ((l0 * 2) ^ ((d & 7) << 4))) = f.s; \
        }                                                                      \
        /* issue next tile's loads (v dead); stay in flight across barriers */ \
        if ((TCUR) + 1 < ntile) {                                              \
            const int p0n = (tile0 + (TCUR) + 1) * TL_;                        \
            _Pragma("unroll")                                                  \
            for (int r = 0; r < 8; ++r)                                        \
                v[r] = *(const float4*)(xb + (size_t)(8 * q + r) * L_ + p0n + l0); \
        }                                                                      \
        BARX();  /* A: tile staged (red4/L1/L2 visible) */                     \
        if (t < TL_) {                                                         \
            const float ss = red4[0][t] + red4[1][t] + red4[2][t] + red4[3][t]; \
            nrm_lds[t] = fmaxf(sqrtf(ss), 1e-12f);                             \
        }                                                                      \
        /* phase 1: R = W * X (quadrant Mt x Nt), contraction dk=128 */        \
        f32x16 r1 = {0};                                                       \
        {                                                                      \
            const int l = 32 * (wv >> 1) + lm;                                 \
            const int rowoff = l * 256;                                        \
            const int swz = (l & 15) << 4;                                     \
            __builtin_amdgcn_s_setprio(1);                                     \
            _Pragma("unroll")                                                  \
            for (int ks = 0; ks < 8; ++ks) {                                   \
                const short8 bfr = *(short8*)((char*)L1b + rowoff + (((16 * ks + 8 * lg) * 2) ^ swz)); \
                r1 = __builtin_amdgcn_mfma_f32_32x32x16_bf16(wf[ks], bfr, r1, 0, 0, 0); \
            }                                                                  \
            __builtin_amdgcn_s_setprio(0);                                     \
        }                                                                      \
        const int myl = 32 * (wv >> 1) + lm;                                   \
        const float ss16 = red4[0][myl] + red4[1][myl] + red4[2][myl] + red4[3][myl]; \
        const float invp = 1.f / fmaxf(sqrtf(ss16), 1e-12f);                   \
        /* softmax over k (no max-sub; |logit*inv| <= ||w_k|| ~ 0.6) */        \
        float e[16];                                                           \
        float s = 0.f;                                                         \
        _Pragma("unroll")                                                      \
        for (int r = 0; r < 16; ++r) { e[r] = __expf(r1[r] * invp); s += e[r]; } \
        s += __shfl_xor(s, 32);                                                \
        if (lane < 32) dred[wv][lm] = s;                                       \
        BARX();  /* B: dred ready (red4 consumed) */                           \
        const float denom = dred[wv][lm] + dred[wv ^ 1][lm];                   \
        const float sc = invp / denom;                                         \
        {                                                                      \
            const int colp = 32 * (wv >> 1) + lm;                              \
            _Pragma("unroll")                                                  \
            for (int rr = 0; rr < 8; ++rr) {                                   \
                const int r = 2 * rr;                                          \
                const int k = 32 * Mt + (r & 3) + 8 * (r >> 2) + 4 * lg;       \
                const unsigned u = pk2(e[r] * sc, e[r + 1] * sc);              \
                AsS[k * ASH + colp]       = (short)u;                          \
                AsS[(k + 1) * ASH + colp] = (short)(u >> 16);                  \
            }                                                                  \
        }                                                                      \
        BARX();  /* C: A_s ready */                                            \
        /* phase 2: V += A_s * X^T, contraction l=64 */                        \
        {                                                                      \
            short8 af[4];                                                      \
            const char* arow = AsRaw + (size_t)(32 * Mt + lm) * (ASH * 2);     \
            _Pragma("unroll")                                                  \
            for (int ks = 0; ks < 4; ++ks)                                     \
                af[ks] = *(const short8*)(arow + (16 * ks + 8 * lg) * 2);      \
            __builtin_amdgcn_s_setprio(1);                                     \
            _Pragma("unroll")                                                  \
            for (int nt = 0; nt < 2; ++nt) {                                   \
                const int dk = 32 * (2 * (wv >> 1) + nt) + lm;                 \
                const int rowoff = dk * 128;                                   \
                const int swz = (dk & 7) << 4;                                 \
                f32x16 a = (nt == 0) ? acc0 : acc1;                            \
                _Pragma("unroll")                                              \
                for (int ks = 0; ks < 4; ++ks) {                               \
                    const short8 bfr = *(short8*)((char*)L2b + rowoff + (((16 * ks + 8 * lg) * 2) ^ swz)); \
                    a = __builtin_amdgcn_mfma_f32_32x32x16_bf16(af[ks], bfr, a, 0, 0, 0); \
                }                                                              \
                if (nt == 0) acc0 = a; else acc1 = a;                          \
            }                                                                  \
            __builtin_amdgcn_s_setprio(0);                                     \
        }                                                                      \
        /* asum partial: asum[k] += sum_l A_s[k][l]*nrm[l] (vector reads) */   \
        {                                                                      \
            const int k  = 16 * wv + (lane & 15);                              \
            const int c4 = lane >> 4;                                          \
            const char* ap = AsRaw + (size_t)k * (ASH * 2) + c4 * 32;          \
            const short8 a0 = *(const short8*)ap;                              \
            const short8 a1 = *(const short8*)(ap + 16);                       \
            const float4* np = (const float4*)&nrm_lds[16 * c4];               \
            const float4 n0 = np[0], n1 = np[1], n2 = np[2], n3 = np[3];       \
            float ps = 0.f;                                                    \
            ps = fmaf(bf2f(a0[0]), n0.x, ps); ps = fmaf(bf2f(a0[1]), n0.y, ps); \
            ps = fmaf(bf2f(a0[2]), n0.z, ps); ps = fmaf(bf2f(a0[3]), n0.w, ps); \
            ps = fmaf(bf2f(a0[4]), n1.x, ps); ps = fmaf(bf2f(a0[5]), n1.y, ps); \
            ps = fmaf(bf2f(a0[6]), n1.z, ps); ps = fmaf(bf2f(a0[7]), n1.w, ps); \
            ps = fmaf(bf2f(a1[0]), n2.x, ps); ps = fmaf(bf2f(a1[1]), n2.y, ps); \
            ps = fmaf(bf2f(a1[2]), n2.z, ps); ps = fmaf(bf2f(a1[3]), n2.w, ps); \
            ps = fmaf(bf2f(a1[4]), n3.x, ps); ps = fmaf(bf2f(a1[5]), n3.y, ps); \
            ps = fmaf(bf2f(a1[6]), n3.z, ps); ps = fmaf(bf2f(a1[7]), n3.w, ps); \
            ps += __shfl_xor(ps, 16);                                          \
            ps += __shfl_xor(ps, 32);                                          \
            asum_acc += ps;                                                    \
        }                                                                      \
        /* no barrier D: next staging writes the other LDS buffer */           \
    }

// Full-MFMA fused NetVLAD main (r13 + LDS double-buffer, 3 barriers/tile).
__global__ __launch_bounds__(256, 2)
void vlad_main(const float* __restrict__ x, const float* __restrict__ w,
               short* __restrict__ vout, float* __restrict__ aout)
{
    __shared__ __align__(16) short L1[2][TL_ * D_];  // [l][dk] bf16, swz ^((l&15)<<4), 2x16KB
    __shared__ __align__(16) short L2[2][D_ * TL_];  // [dk][l] bf16, swz ^((dk&7)<<4), 2x16KB
    __shared__ __align__(16) char  AsRaw[K_ * ASH * 2];  // bf16 a*inv [k][p], 9.2KB
    __shared__ __align__(16) float red4[4][TL_];     // per-wave 32-d sumsq partials, 1KB
    __shared__ __align__(16) float nrm_lds[TL_];
    __shared__ float dred[4][32];                    // softmax denominator exchange

    const int t    = threadIdx.x;
    const int lane = t & 63;
    const int wv   = __builtin_amdgcn_readfirstlane(t >> 6);  // 0..3
    const int n    = blockIdx.x / NG_;
    const int g    = blockIdx.x % NG_;
    const int tile0 = (g == 0) ? 0 : (7 + 6 * (g - 1));
    const int ntile = (g == 0) ? 7 : 6;

    const int Mt = wv & 1;     // cluster-half (M) for both phases
    const int lg = lane >> 5;  // k-element group (0/1)
    const int lm = lane & 31;

    short* AsS = (short*)AsRaw;

    // ---- W fragments, loop-invariant, kept in 32 VGPRs ----
    short8 wf[8];
#pragma unroll
    for (int ks = 0; ks < 8; ++ks) {
        const float* wp = w + (size_t)(32 * Mt + lm) * D_ + 16 * ks + 8 * lg;
        const float4 wa = *(const float4*)wp;
        const float4 wb = *(const float4*)(wp + 4);
        union { unsigned u[4]; short8 s; } f;
        f.u[0] = pk2(wa.x, wa.y); f.u[1] = pk2(wa.z, wa.w);
        f.u[2] = pk2(wb.x, wb.y); f.u[3] = pk2(wb.z, wb.w);
        wf[ks] = f.s;
    }

    f32x16 acc0 = {0};   // V[k][d] C-frag, d-tile 2*(wv>>1)
    f32x16 acc1 = {0};   // d-tile 2*(wv>>1)+1
    float asum_acc = 0.f;

    const int q  = t >> 4;          // staging: d-rows 8q..8q+7
    const int l0 = (t & 15) * 4;    // staging: 4 pixels
    const float* xb = x + (size_t)n * D_ * L_;

    // ---- prologue: load tile 0 into registers ----
    float4 v[8];
    {
        const int p0 = tile0 * TL_;
#pragma unroll
        for (int r = 0; r < 8; ++r)
            v[r] = *(const float4*)(xb + (size_t)(8 * q + r) * L_ + p0 + l0);
    }

    for (int tp = 0; tp < ntile; tp += 2) {
        PROCESS(tp, L1[0], L2[0])
        if (tp + 1 < ntile) {
            PROCESS(tp + 1, L1[1], L2[1])
        }
    }

    // ---- commit: per-group bf16 slab (plain stores) ----
    {
        const int dbase0 = 32 * (2 * (wv >> 1));
        short* vb2 = vout + (size_t)g * VSLAB;
#pragma unroll
        for (int r = 0; r < 16; ++r) {
            const int k = 32 * Mt + (r & 3) + 8 * (r >> 2) + 4 * lg;
            short* row = vb2 + ((size_t)n * K_ + k) * D_ + lm;
            const unsigned u = pk2(acc0[r], acc1[r]);
            row[dbase0]      = (short)u;
            row[dbase0 + 32] = (short)(u >> 16);
        }
        if (lane < 16) {
            const int k = 16 * wv + lane;
            aout[(size_t)g * (N_ * K_) + n * K_ + k] = asum_acc;
        }
    }
}

// Finalize, spread: one block per (n, k-octet). Sum bf16 slabs, subtract a*c,
// intra-normalize over d. Global norm = sqrt(K) = 8 exactly (unit rows).
__global__ __launch_bounds__(256)
void vlad_fin(const short* __restrict__ vacc, const float* __restrict__ asum,
              const float* __restrict__ cent, float* __restrict__ out)
{
    const int t   = threadIdx.x;
    const int b   = blockIdx.x;
    const int n   = b >> 3;
    const int oct = b & 7;
    const int k   = oct * 8 + (t >> 5);   // 8 k-rows per block
    const int c   = t & 31;               // float4 column; d = 4c

    float a = 0.f;
#pragma unroll
    for (int g = 0; g < NG_; ++g) a += asum[(size_t)g * (N_ * K_) + n * K_ + k];

    const size_t roff = ((size_t)(n * K_ + k)) * D_ + c * 4;
    float4 v = make_float4(0.f, 0.f, 0.f, 0.f);
#pragma unroll
    for (int g = 0; g < NG_; ++g) {
        const short4v s = *(const short4v*)(vacc + (size_t)g * VSLAB + roff);
        v.x += bf2f(s[0]); v.y += bf2f(s[1]);
        v.z += bf2f(s[2]); v.w += bf2f(s[3]);
    }
    const float4 cc = ((const float4*)cent)[((size_t)k * D_ >> 2) + c];
    v.x -= a * cc.x; v.y -= a * cc.y; v.z -= a * cc.z; v.w -= a * cc.w;
    float ss = v.x * v.x + v.y * v.y + v.z * v.z + v.w * v.w;
    ss += __shfl_xor(ss, 1);
    ss += __shfl_xor(ss, 2);
    ss += __shfl_xor(ss, 4);
    ss += __shfl_xor(ss, 8);
    ss += __shfl_xor(ss, 16);             // stays within the 32-lane row group
    const float s1 = 0.125f / fmaxf(sqrtf(ss), 1e-12f);   // intra-norm * 1/sqrt(K)
    float4 o;
    o.x = v.x * s1; o.y = v.y * s1; o.z = v.z * s1; o.w = v.w * s1;
    *(float4*)(out + roff) = o;
}

extern "C" void kernel_launch(void* const* d_in, const int* in_sizes, int n_in,
                              void* d_out, int out_size, void* d_ws, size_t ws_size,
                              hipStream_t stream)
{
    const float* x = (const float*)d_in[0];   // [N, D, H, W]
    const float* w = (const float*)d_in[1];   // [K, D]
    const float* c = (const float*)d_in[2];   // [K, D]
    float* out = (float*)d_out;               // [N, K*D]

    short* vacc = (short*)d_ws;                          // NG bf16 V slabs (8.4MB)
    float* ap   = (float*)(vacc + NG_ * VSLAB);          // NG f32 asum slabs (131KB)

    vlad_main<<<dim3(N_ * NG_), dim3(256), 0, stream>>>(x, w, vacc, ap);
    vlad_fin<<<dim3(N_ * 8), dim3(256), 0, stream>>>(vacc, ap, c, out);
}